// Round 9
// baseline (1287.052 us; speedup 1.0000x reference)
//
#include <hip/hip_runtime.h>
#include <stdint.h>

#define OUTF 11008
#define INF  4096
#define NG   32      // groups = INF/128
#define TOK  8192
#define KB4  2048    // int32 per qweight row = INF/2

// ---- main GEMM geometry: 256x256 tile, 8 waves, 8-phase, 32x32x16 MFMA ----
#define BM 256
#define BN 256
#define BK 64
#define NT (INF / BK)    // 64 K-tiles
#define GX (OUTF / BN)   // 43
#define GY (TOK / BM)    // 32
#define NWG (GX * GY)    // 1376 = 8 XCD chunks x 172

typedef unsigned short u16;
typedef __attribute__((ext_vector_type(8))) short bf16x8;
typedef __attribute__((ext_vector_type(4))) float f32x4;
typedef __attribute__((ext_vector_type(16))) float f32x16;
typedef __attribute__((ext_vector_type(4))) int i32x4;

// fp32 -> bf16 round-to-nearest-even (inputs finite)
__device__ inline u16 f2bf(float f) {
  union { float f; uint32_t u; } v; v.f = f;
  return (u16)((v.u + 0x7fff + ((v.u >> 16) & 1)) >> 16);
}

// async global->LDS, 16B per lane; lds dest must be wave-uniform base (+lane*16 implicit)
__device__ inline void async_copy16(const void* g, const void* l) {
  __builtin_amdgcn_global_load_lds(
      (__attribute__((address_space(1))) void*)(g),
      (__attribute__((address_space(3))) void*)(l), 16, 0, 0);
}

#define FENCE() asm volatile("" ::: "memory")
#define BAR()   do { FENCE(); __builtin_amdgcn_s_barrier(); FENCE(); } while (0)
#define VMCNT(n) asm volatile("s_waitcnt vmcnt(" #n ")" ::: "memory")

// dequant 8 int4 (one u32 = 8 nibbles, nibble i = weight i) -> bf16x8
// w = fmaf((float)n, s, zs) with zs = -z*s : identical math to the old prep,
// so bf16 results are bit-identical (v_cvt_pk_bf16_f32 is RNE).
__device__ inline bf16x8 dq8(uint32_t u, float s, float zs) {
  union { uint32_t w[4]; bf16x8 v; } r;
#pragma unroll
  for (int i = 0; i < 4; ++i) {
    const float f0 = fmaf((float)((u >> (8 * i)) & 15u), s, zs);
    const float f1 = fmaf((float)((u >> (8 * i + 4)) & 15u), s, zs);
    uint32_t p;
    asm("v_cvt_pk_bf16_f32 %0, %1, %2" : "=v"(p) : "v"(f0), "v"(f1));
    r.w[i] = p;
  }
  return r.v;
}

// ---------------- fused preprocessing kernel ----------------
// Pass 1: X fp32 -> bf16 (unchanged).
// Pass 2: QW int32 (1 useful byte each) -> TRUE-packed bytes Wp, with the
//   gemm's B bank-swizzle baked in: within each 32-B row-chunk (8 granules of
//   4 B), phys granule p holds logical granule p ^ swz(o),
//   swz(o) = (o&7) ^ ((o>>3)&3).  (prep writes any layout for free)
// Pass 3: SZ[g][o] = (s, -z*s) float2 table (group-major for coalesced
//   per-group staging in gemm).

#define NXU ((long long)TOK * INF / 4)        // 8,388,608 x-units (4 f32)
#define NWU2 ((long long)OUTF * 64)           // 704,512 w-chunks (32 B out)
#define NSZ ((long long)OUTF * NG)            // 352,256 sz-units
#define PREPBLK 2048

__global__ __launch_bounds__(256) void prep(const float* __restrict__ X,
                                            const int* __restrict__ QW,
                                            const float* __restrict__ scales,
                                            const float* __restrict__ zeros,
                                            u16* __restrict__ Xb,
                                            unsigned char* __restrict__ Wp,
                                            float2* __restrict__ SZ) {
  const long long stride = (long long)gridDim.x * 256;
  for (long long i = (long long)blockIdx.x * 256 + threadIdx.x;
       i < NXU + NWU2 + NSZ; i += stride) {
    if (i < NXU) {
      const f32x4 f = __builtin_nontemporal_load((const f32x4*)X + i);
      union { u16 t[4]; uint2 v; } u;
      u.t[0] = f2bf(f[0]); u.t[1] = f2bf(f[1]);
      u.t[2] = f2bf(f[2]); u.t[3] = f2bf(f[3]);
      ((uint2*)Xb)[i] = u.v;
    } else if (i < NXU + NWU2) {
      const long long j = i - NXU;           // w-chunk: row o, 32-B chunk c32
      const int o = (int)(j >> 6);
      const int c32 = (int)j & 63;
      const int swz = (o & 7) ^ ((o >> 3) & 3);
      const i32x4* qp = (const i32x4*)(QW + (size_t)o * KB4 + c32 * 32);
      uint32_t dw[8];
#pragma unroll
      for (int k = 0; k < 8; ++k) {          // granule k = 4 int32 -> 4 bytes
        const i32x4 q = __builtin_nontemporal_load(qp + k);
        dw[k] = (uint32_t)(q[0] & 255) | ((uint32_t)(q[1] & 255) << 8) |
                ((uint32_t)(q[2] & 255) << 16) | ((uint32_t)(q[3] & 255) << 24);
      }
      union { uint32_t d[8]; i32x4 v[2]; } u;
#pragma unroll
      for (int p = 0; p < 8; ++p) u.d[p] = dw[p ^ swz];
      i32x4* op = (i32x4*)(Wp + (size_t)o * KB4 + c32 * 32);
      op[0] = u.v[0];
      op[1] = u.v[1];
    } else {
      const long long k = i - NXU - NWU2;
      const int g = (int)(k / OUTF);
      const int o = (int)(k % OUTF);
      const float s = scales[(size_t)o * NG + g];
      const float z = zeros[(size_t)o * NG + g];
      float2 v; v.x = s; v.y = -z * s;
      SZ[(size_t)g * OUTF + o] = v;
    }
  }
}

// ---------------- main GEMM: r8 schedule + packed-B-in-LDS + reg dequant ----
// A path identical to r8 (swizzle conflict-free, counter-verified 0).
// B: packed bytes in LDS (8 KB/tile, ONE global_load_lds), per-lane u32 pulls
// (conflict-free: bank = 8(n&3) + g^(n&7)^((n>>3)&3), bijective per 32 lanes),
// dequant to bf16 frags in registers (dq8). (s, zs) via small LDS-staged table.
//
// Per iter (tiles t->Bp[0]/As[0] "S0", t+1->Bp[1]/As[1] "S1"), 8 phases:
// B-set prep (read u32s at p-pre, dequant at p-post, use from p+2):
//   ph0: B(t)KS1 -> setB (used ph2,ph3)   ph2: B(t+1)KS0 -> setA (ph4,ph5)
//   ph4: B(t+1)KS1 -> setB (ph6,ph7)      ph6: B(t+2)KS0 -> setA (next ph0,ph1)
// Stage plan:  ph0: A(t+1)mh0   ph1: A(t+1)mh1 + B(t+2) + SZ(t+2)
//              ph3: A(t+2)mh0   ph4: A(t+2)mh1   ph5: B(t+3)
// Waits: ph3 VMCNT(2) (drains <=ph1: certifies A(t+1), B(t+2), SZ for ph4+),
//        ph7 VMCNT(0) (queue = ph3/ph4/ph5 loads, all >=2 phases old ->
//        counted-complete; certifies everything next iter's ph0-ph3 read).
// Cross-wave visibility: every LDS region is read only after a VMCNT+BAR pair
// that covers ALL waves' staging of it (audited per region above).
// WAR: every stage lands >=1 end-barrier after the region's last read phase.

__global__ __launch_bounds__(512, 2) void gemm_pre512(
    const u16* __restrict__ A, const unsigned char* __restrict__ W,
    const float2* __restrict__ SZg, const float* __restrict__ bias,
    float* __restrict__ C) {
  __shared__ __align__(16) u16 As[2][BM * BK];          // 64 KB
  __shared__ __align__(16) unsigned char Bp[2][8192];   // 16 KB
  __shared__ __align__(16) float2 Sz[2][4][256];        // 16 KB (4 copies: no DMA races)
  const int tid = threadIdx.x;
  const int lane = tid & 63;
  const int wid = __builtin_amdgcn_readfirstlane(tid >> 6);

  // XCD-local 2D grouping (r6): XCD k owns bm in [4k,4k+4); 4bm x 8bn walks.
  const int lin = blockIdx.x;
  const int xcd = lin & 7;
  const int wgc = lin >> 3;                 // 0..171
  int bmr, bn;
  if (wgc < 160) {
    const int g = wgc >> 5, r = wgc & 31;
    bn = g * 8 + (r & 7);
    bmr = r >> 3;
  } else {
    const int r = wgc - 160;
    bn = 40 + r % 3;
    bmr = r / 3;
  }
  const int bm = xcd * 4 + bmr;

  const u16* Ab = A + (size_t)bm * BM * INF;

  // A staging (r8 verbatim): pre-swizzled source granule, linear LDS dest
  const int rowoff = tid >> 3;
  const int gran = (tid & 7) ^ (rowoff & 7) ^ ((rowoff >> 3) & 3);
  const u16* Asrc = Ab + (size_t)rowoff * INF + gran * 8;
  const int wid8 = wid * 8;

  // B staging: one call per tile; lane covers row tid>>1, 16-B half tid&1
  // (source layout is phys-granule-ordered already -> verbatim 16-B copy)
  const unsigned char* Bsrc2 =
      W + ((size_t)(bn * BN + (tid >> 1))) * KB4 + (tid & 1) * 16;
  // SZ staging: wave w -> copy w>>1, half w&1; lane covers rows lane*2..+2
  const char* SZsrc = (const char*)SZg +
      ((size_t)(bn * BN + (wid & 1) * 128 + lane * 2)) * 8;

  // frag addressing (32x32)
  const int rr32 = lane & 31;
  const int hi = lane >> 5;
  const int xr = (rr32 & 7) ^ ((rr32 >> 3) & 3);
  const int wm = wid >> 2;
  const int wn = wid & 3;
  const int bB = (wn * 64 + rr32) * 32;     // packed-B lane row base (bytes)

  f32x16 acc[4][2] = {};
  bf16x8 setA[2][2], setB[2][2];            // B frag sets [nt][ks]
  float2 szc[2], szn[2];                    // (s, zs) for rows nt=0,1
  uint32_t ub[4];                           // packed-B staging regs

#define STAGE1(LDS, SRC, TT, R0)                                               \
  async_copy16((SRC) + (size_t)(R0) * INF + (size_t)(TT) * BK,                 \
               (const char*)(LDS) + ((R0) + wid8) * 128);
#define STAGE_B(S, TT)                                                         \
  async_copy16(Bsrc2 + (size_t)(TT) * 32, (const char*)&Bp[S][0] + wid * 1024);
#define STAGE_SZ(SLOT, G)                                                      \
  async_copy16(SZsrc + (size_t)(G) * (OUTF * 8),                               \
               (const char*)&Sz[SLOT][wid >> 1][(wid & 1) * 128]);

#define RD_A(DST, S, KS2, MH)                                                  \
  _Pragma("unroll") for (int mi = 0; mi < 2; ++mi)                             \
    _Pragma("unroll") for (int ks = 0; ks < 2; ++ks)                           \
      DST[mi][ks] = *(const bf16x8*)&As[S][                                    \
          (wm * 128 + ((MH) * 2 + mi) * 32 + rr32) * BK +                      \
          ((((KS2) * 4 + ks * 2 + hi) ^ xr) * 8)];

#define RD_BU(S, KS2)                                                          \
  _Pragma("unroll") for (int nt = 0; nt < 2; ++nt)                             \
    _Pragma("unroll") for (int ks = 0; ks < 2; ++ks)                           \
      ub[nt * 2 + ks] = *(const uint32_t*)&Bp[S][                              \
          bB + nt * 1024 + ((((KS2) * 4 + ks * 2 + hi) ^ xr) * 4)];

#define DQ_SET(SET, SZV)                                                       \
  _Pragma("unroll") for (int nt = 0; nt < 2; ++nt)                             \
    _Pragma("unroll") for (int ks = 0; ks < 2; ++ks)                           \
      SET[nt][ks] = dq8(ub[nt * 2 + ks], SZV[nt].x, SZV[nt].y);

#define RD_SZ(DST, SLOT)                                                       \
  do {                                                                         \
    DST[0] = Sz[SLOT][0][wn * 64 + rr32];                                      \
    DST[1] = Sz[SLOT][0][wn * 64 + 32 + rr32];                                 \
  } while (0)

#define MFMA8(AF, BQ, MH)                                                      \
  do {                                                                         \
    __builtin_amdgcn_s_setprio(1);                                             \
    _Pragma("unroll") for (int ks = 0; ks < 2; ++ks)                           \
      _Pragma("unroll") for (int mi = 0; mi < 2; ++mi)                         \
        _Pragma("unroll") for (int ni = 0; ni < 2; ++ni)                       \
          acc[(MH) * 2 + mi][ni] = __builtin_amdgcn_mfma_f32_32x32x16_bf16(    \
              AF[mi][ks], BQ[ni][ks], acc[(MH) * 2 + mi][ni], 0, 0, 0);        \
    __builtin_amdgcn_s_setprio(0);                                             \
  } while (0)

  // prologue: A(0) both regions, B(0), B(1), SZ(0); drain all; prep setA(t=0).
  STAGE1(&As[0][0], Asrc, 0, 0)   STAGE1(&As[0][0], Asrc, 0, 128)
  STAGE1(&As[0][0], Asrc, 0, 64)  STAGE1(&As[0][0], Asrc, 0, 192)
  STAGE_B(0, 0) STAGE_B(1, 1)
  STAGE_SZ(0, 0)
  VMCNT(0);
  BAR();
  RD_SZ(szc, 0);
  RD_BU(0, 0);
  DQ_SET(setA, szc);

  for (int t = 0; t < NT; t += 2) {
    const int more = (t + 2 < NT);
    // ph0: (S0,KS0,mh0) | read B(t)KS1 | stage A(t+1)mh0 | post: dq -> setB
    {
      bf16x8 af[2][2];
      RD_A(af, 0, 0, 0)
      RD_BU(0, 1)
      STAGE1(&As[1][0], Asrc, t + 1, 0) STAGE1(&As[1][0], Asrc, t + 1, 128)
      BAR(); MFMA8(af, setA, 0);
      DQ_SET(setB, szc);
      BAR();
    }
    // ph1: (S0,KS0,mh1) | stage A(t+1)mh1 + B(t+2) + SZ(t+2)
    {
      bf16x8 af[2][2];
      RD_A(af, 0, 0, 1)
      STAGE1(&As[1][0], Asrc, t + 1, 64) STAGE1(&As[1][0], Asrc, t + 1, 192)
      if (more) {
        STAGE_B(0, t + 2)
        STAGE_SZ(((t >> 1) + 1) & 1, (t >> 1) + 1)
      }
      BAR(); MFMA8(af, setA, 1); BAR();
    }
    // ph2: (S0,KS1,mh0) | read B(t+1)KS0 | post: dq -> setA
    {
      bf16x8 af[2][2];
      RD_A(af, 0, 1, 0)
      RD_BU(1, 0)
      BAR(); MFMA8(af, setB, 0);
      DQ_SET(setA, szc);
      BAR();
    }
    // ph3: (S0,KS1,mh1) | stage A(t+2)mh0 | VMCNT(2) post-MFMA
    {
      bf16x8 af[2][2];
      RD_A(af, 0, 1, 1)
      if (more) { STAGE1(&As[0][0], Asrc, t + 2, 0) STAGE1(&As[0][0], Asrc, t + 2, 128) }
      BAR(); MFMA8(af, setB, 1);
      if (more) { VMCNT(2); } else { VMCNT(0); }
      BAR();
    }
    // ph4: (S1,KS0,mh0) | read B(t+1)KS1 | stage A(t+2)mh1 | post: dq -> setB
    {
      bf16x8 af[2][2];
      RD_A(af, 1, 0, 0)
      RD_BU(1, 1)
      if (more) { STAGE1(&As[0][0], Asrc, t + 2, 64) STAGE1(&As[0][0], Asrc, t + 2, 192) }
      BAR(); MFMA8(af, setA, 0);
      DQ_SET(setB, szc);
      BAR();
    }
    // ph5: (S1,KS0,mh1) | stage B(t+3)
    {
      bf16x8 af[2][2];
      RD_A(af, 1, 0, 1)
      if (more) { STAGE_B(1, t + 3) }
      BAR(); MFMA8(af, setA, 1); BAR();
    }
    // ph6: (S1,KS1,mh0) | read B(t+2)KS0 + next SZ | post: dq -> setA
    {
      bf16x8 af[2][2];
      RD_A(af, 1, 1, 0)
      if (more) {
        RD_BU(0, 0)
        RD_SZ(szn, ((t >> 1) + 1) & 1);
      }
      BAR(); MFMA8(af, setB, 0);
      if (more) { DQ_SET(setA, szn); }
      BAR();
    }
    // ph7: (S1,KS1,mh1) | VMCNT(0) post-MFMA (queue all >=2 phases old)
    {
      bf16x8 af[2][2];
      RD_A(af, 1, 1, 1)
      BAR(); MFMA8(af, setB, 1);
      VMCNT(0);
      BAR();
    }
    if (more) { szc[0] = szn[0]; szc[1] = szn[1]; }
  }

  // epilogue: NT stores; 32x32 C/D layout col=lane&31,
  // row = (reg&3) + 8*(reg>>2) + 4*hi
  float bv[2];
#pragma unroll
  for (int ni = 0; ni < 2; ++ni)
    bv[ni] = bias[bn * BN + wn * 64 + ni * 32 + rr32];
#pragma unroll
  for (int mt = 0; mt < 4; ++mt)
#pragma unroll
    for (int ni = 0; ni < 2; ++ni) {
      const int gn = bn * BN + wn * 64 + ni * 32 + rr32;
#pragma unroll
      for (int reg = 0; reg < 16; ++reg) {
        const int gm = bm * BM + wm * 128 + mt * 32 +
                       (reg & 3) + 8 * (reg >> 2) + 4 * hi;
        __builtin_nontemporal_store(acc[mt][ni][reg] + bv[ni],
                                    &C[(size_t)gm * OUTF + gn]);
      }
    }
}

// ---------------- fused fallback (no workspace requirement) ----------------

#define FBM 128
#define FBN 128

#define FMFMA_COMPUTE()                                                       \
  do {                                                                        \
    const int frr = lane & 15;                                                \
    const int fq4 = lane >> 4;                                                \
    _Pragma("unroll") for (int ks = 0; ks < 2; ++ks) {                        \
      bf16x8 fa[4], fb[4];                                                    \
      const int kk = (((ks * 4 + fq4) ^ (frr & 7)) * 8);                      \
      _Pragma("unroll") for (int i = 0; i < 4; ++i) {                         \
        fa[i] = *(const bf16x8*)&Asf[(mwave + i * 16 + frr) * BK + kk];       \
        fb[i] = *(const bf16x8*)&Bsf[(nwave + i * 16 + frr) * BK + kk];       \
      }                                                                       \
      _Pragma("unroll") for (int mi = 0; mi < 4; ++mi)                        \
        _Pragma("unroll") for (int ni = 0; ni < 4; ++ni)                      \
          facc[mi][ni] = __builtin_amdgcn_mfma_f32_16x16x32_bf16(             \
              fa[mi], fb[ni], facc[mi][ni], 0, 0, 0);                         \
    }                                                                         \
  } while (0)

__global__ __launch_bounds__(256) void gemm_fused(const float* __restrict__ X,
                                                  const int* __restrict__ QW,
                                                  const float* __restrict__ scales,
                                                  const float* __restrict__ zeros,
                                                  const float* __restrict__ bias,
                                                  float* __restrict__ C) {
  __shared__ __align__(16) u16 Asf[FBM * BK];
  __shared__ __align__(16) u16 Bsf[FBN * BK];
  const int tid = threadIdx.x;
  const int lane = tid & 63;
  const int wid = tid >> 6;
  const int bm = blockIdx.y, bn = blockIdx.x;
  const int row = tid >> 1;
  const int half = tid & 1;
  const float* xr = X + (size_t)(bm * FBM + row) * INF + half * 32;
  const int* qr = QW + (size_t)(bn * FBN + row) * KB4 + half * 16;
  const float* srow = scales + (size_t)(bn * FBN + row) * NG;
  const float* zrow = zeros + (size_t)(bn * FBN + row) * NG;
  const int mwave = (wid >> 1) * 64;
  const int nwave = (wid & 1) * 64;
  f32x4 facc[4][4] = {};

  for (int kb = 0; kb < INF / BK; ++kb) {
    const int k0 = kb * BK;
    union { u16 t[32]; int4 v[4]; } ta, tb;
#pragma unroll
    for (int j = 0; j < 8; ++j) {
      const float4 f = *(const float4*)(xr + k0 + j * 4);
      ta.t[4 * j]     = f2bf(f.x);
      ta.t[4 * j + 1] = f2bf(f.y);
      ta.t[4 * j + 2] = f2bf(f.z);
      ta.t[4 * j + 3] = f2bf(f.w);
    }
    {
      const float s = srow[kb >> 1];
      const float zs = -zrow[kb >> 1] * s;
#pragma unroll
      for (int j = 0; j < 4; ++j) {
        const int4 q = *(const int4*)(qr + kb * 32 + j * 4);
        const int qq[4] = {q.x, q.y, q.z, q.w};
#pragma unroll
        for (int u = 0; u < 4; ++u) {
          tb.t[8 * j + 2 * u]     = f2bf(fmaf((float)(qq[u] & 15), s, zs));
          tb.t[8 * j + 2 * u + 1] = f2bf(fmaf((float)((qq[u] >> 4) & 15), s, zs));
        }
      }
    }
    __syncthreads();
#pragma unroll
    for (int j = 0; j < 4; ++j) {
      *(int4*)&Asf[row * BK + (((half * 4 + j) ^ (row & 7)) * 8)] = ta.v[j];
      *(int4*)&Bsf[row * BK + (((half * 4 + j) ^ (row & 7)) * 8)] = tb.v[j];
    }
    __syncthreads();
    FMFMA_COMPUTE();
  }
  {
    const int ncol = lane & 15;
    const int qrow = (lane >> 4) * 4;
#pragma unroll
    for (int mi = 0; mi < 4; ++mi)
#pragma unroll
      for (int ni = 0; ni < 4; ++ni) {
        const int gn = bn * FBN + nwave + ni * 16 + ncol;
        const float bvv = bias[gn];
#pragma unroll
        for (int r = 0; r < 4; ++r) {
          const int gm = bm * FBM + mwave + mi * 16 + qrow + r;
          C[(size_t)gm * OUTF + gn] = facc[mi][ni][r] + bvv;
        }
      }
  }
}

// ---------------- launch ----------------

extern "C" void kernel_launch(void* const* d_in, const int* in_sizes, int n_in,
                              void* d_out, int out_size, void* d_ws, size_t ws_size,
                              hipStream_t stream) {
  const float* x = (const float*)d_in[0];
  const int* qw = (const int*)d_in[1];
  const float* scales = (const float*)d_in[2];
  const float* zeros = (const float*)d_in[3];
  const float* bias = (const float*)d_in[4];
  float* out = (float*)d_out;

  const size_t needX = (size_t)TOK * INF * sizeof(u16);     // 67,108,864 B
  const size_t needWp = (size_t)OUTF * KB4;                 // 22,544,384 B
  const size_t needSZ = (size_t)OUTF * NG * sizeof(float2); //  2,818,048 B

  if (ws_size >= needX + needWp + needSZ) {
    u16* Xb = (u16*)d_ws;
    unsigned char* Wp = (unsigned char*)d_ws + needX;
    float2* SZ = (float2*)((char*)d_ws + needX + needWp);
    prep<<<PREPBLK, 256, 0, stream>>>(x, qw, scales, zeros, Xb, Wp, SZ);
    gemm_pre512<<<dim3(NWG), 512, 0, stream>>>(Xb, Wp, SZ, bias, out);
  } else {
    gemm_fused<<<dim3(OUTF / FBN, TOK / FBM), 256, 0, stream>>>(x, qw, scales, zeros, bias, out);
  }
}

// Round 10
// 1215.768 us; speedup vs baseline: 1.0586x; 1.0586x over previous
//
#include <hip/hip_runtime.h>
#include <stdint.h>

#define OUTF 11008
#define INF  4096
#define NG   32      // groups = INF/128
#define TOK  8192
#define KB4  2048    // int32 per qweight row = INF/2

// ---- main GEMM geometry: 128x256 tile, 8 waves, BK=32, 2 blocks/CU ----
#define BM 128
#define BN 256
#define BK 32
#define NT (INF / BK)    // 128 K-tiles
#define GX (OUTF / BN)   // 43
#define GY (TOK / BM)    // 64
#define NWG (GX * GY)    // 2752 = 8 XCD chunks x 344

typedef unsigned short u16;
typedef __attribute__((ext_vector_type(8))) short bf16x8;
typedef __attribute__((ext_vector_type(4))) float f32x4;
typedef __attribute__((ext_vector_type(16))) float f32x16;
typedef __attribute__((ext_vector_type(4))) int i32x4;

// fp32 -> bf16 round-to-nearest-even (inputs finite)
__device__ inline u16 f2bf(float f) {
  union { float f; uint32_t u; } v; v.f = f;
  return (u16)((v.u + 0x7fff + ((v.u >> 16) & 1)) >> 16);
}

// async global->LDS, 16B per lane; lds dest must be wave-uniform base (+lane*16 implicit)
__device__ inline void async_copy16(const void* g, const void* l) {
  __builtin_amdgcn_global_load_lds(
      (__attribute__((address_space(1))) void*)(g),
      (__attribute__((address_space(3))) void*)(l), 16, 0, 0);
}

#define FENCE() asm volatile("" ::: "memory")
#define BAR()   do { FENCE(); __builtin_amdgcn_s_barrier(); FENCE(); } while (0)
#define VMCNT(n) asm volatile("s_waitcnt vmcnt(" #n ")" ::: "memory")

// ---------------- fused preprocessing kernel (r6/r8 dense version) ----------------

#define NXU ((long long)TOK * INF / 4)    // 8,388,608
#define NWU ((long long)OUTF * KB4 / 4)   // 5,636,096
#define PREPBLK 2048

__global__ __launch_bounds__(256) void prep(const float* __restrict__ X,
                                            const int* __restrict__ QW,
                                            const float* __restrict__ scales,
                                            const float* __restrict__ zeros,
                                            u16* __restrict__ Xb,
                                            u16* __restrict__ Wb) {
  const long long stride = (long long)gridDim.x * 256;
  for (long long i = (long long)blockIdx.x * 256 + threadIdx.x; i < NXU + NWU;
       i += stride) {
    if (i < NXU) {
      const f32x4 f = __builtin_nontemporal_load((const f32x4*)X + i);
      union { u16 t[4]; uint2 v; } u;
      u.t[0] = f2bf(f[0]); u.t[1] = f2bf(f[1]);
      u.t[2] = f2bf(f[2]); u.t[3] = f2bf(f[3]);
      ((uint2*)Xb)[i] = u.v;
    } else {
      const long long j = i - NXU;          // w-unit: 4 ints of row o
      const int o = (int)(j >> 9);          // 512 units per row (2048/4)
      const int c0 = ((int)j & 511) * 4;    // int column; group = c0/64 (4 | 64)
      const int g = c0 >> 6;
      const float s = scales[o * NG + g];
      const float zs = -zeros[o * NG + g] * s;
      const i32x4 q = __builtin_nontemporal_load((const i32x4*)QW + j);
      union { u16 t[8]; int4 v; } u;
#pragma unroll
      for (int k = 0; k < 4; ++k) {
        u.t[2 * k]     = f2bf(fmaf((float)(q[k] & 15), s, zs));
        u.t[2 * k + 1] = f2bf(fmaf((float)((q[k] >> 4) & 15), s, zs));
      }
      ((int4*)Wb)[j] = u.v;                 // bf16 cols [2*c0, 2*c0+8)
    }
  }
}

// ---------------- main GEMM: 2 blocks/CU, 2-barrier/tile, 32x32x16 MFMA ----------------
// Occupancy axis: 48 KB LDS + acc=64 VGPR/wave + __launch_bounds__(512,4)
// -> 2 independent blocks/CU (4 waves/SIMD). The two blocks are never
// barrier-coupled: when one drains LDS/waits, the other's MFMAs fill the
// SIMD (m114 co-schedule) -- replaces the explicit pipelining that 5 schedule
// variants failed to buy at 1 block/CU.
//
// LDS swizzle (BK=32: 4 granules of 16 B per 64-B row):
//   phys_granule = logical ^ swz(row), swz(row) = ((row>>1)&3) ^ ((row>>3)&3)
// Within any 16-lane b128 read group, (row&1, swz) pairs repeat exactly 2x ->
// 2-way = free (same structure as r8's counter-verified-zero layout). All
// read/stage row bases are multiples of 32 -> swz depends only on rr32/rowoff.
// Write side: pre-swizzled GLOBAL source + linear LDS dest (global_load_lds).
//
// 32x32x16 fragments (verified r7/r8):
//   A: m = lane&31, k = (lane>>5)*8 + j;  B symmetric
//   C/D: col = lane&31, row = (reg&3) + 8*(reg>>2) + 4*(lane>>5)
//
// Per tile t (slot S = t&1): { read 8 frags (A 2mt x 2KS, B 2nt x 2KS),
//   8 MFMA | BAR (reads of S certified) | stage t+2 -> S (A 1 call, B 2 calls),
//   VMCNT(3) = drains t+1's 3 calls (issued one full tile earlier), leaves
//   t+2's 3 in flight -- never 0 mid-loop | BAR (t+1 collectively visible) }.
// WAR: stage of slot S sits after the barrier certifying all waves' reads of S.

__global__ __launch_bounds__(512, 4) void gemm_occ(const u16* __restrict__ A,
                                                   const u16* __restrict__ B,
                                                   const float* __restrict__ bias,
                                                   float* __restrict__ C) {
  __shared__ __align__(16) u16 As[2][BM * BK];   // 2 x 8 KB
  __shared__ __align__(16) u16 Bs[2][BN * BK];   // 2 x 16 KB  (total 48 KB)
  const int tid = threadIdx.x;
  const int lane = tid & 63;
  const int wid = __builtin_amdgcn_readfirstlane(tid >> 6);

  // XCD-local 2D grouping: XCD k owns bm in [8k,8k+8); 8bm x 8bn rectangles
  // (64 wgs = exactly one XCD's resident set at 2 blocks/CU; working set
  // 8 A-panels (8 MB) + 8 B-panels (16 MB) = 24 MB).
  const int lin = blockIdx.x;
  const int xcd = lin & 7;
  const int wgc = lin >> 3;                 // 0..343
  int bmr, bn;
  if (wgc < 320) {
    const int g = wgc >> 6, r = wgc & 63;
    bn = g * 8 + (r & 7);
    bmr = r >> 3;
  } else {
    const int r = wgc - 320;
    bn = 40 + r % 3;
    bmr = r / 3;
  }
  const int bm = xcd * 8 + bmr;

  const u16* Ab = A + (size_t)bm * BM * INF;
  const u16* Bb = B + (size_t)bn * BN * INF;

  // staging: one global_load_lds (512 lanes x 16 B) covers 128 rows x 64 B
  const int rowoff = tid >> 2;              // 0..127
  const int gran = (tid & 3) ^ ((rowoff >> 1) & 3) ^ ((rowoff >> 3) & 3);
  const u16* Asrc = Ab + (size_t)rowoff * INF + gran * 8;
  const u16* Bsrc = Bb + (size_t)rowoff * INF + gran * 8;

  // frag addressing (32x32)
  const int rr32 = lane & 31;
  const int hi = lane >> 5;
  const int xr2 = ((rr32 >> 1) & 3) ^ ((rr32 >> 3) & 3);
  const int wm = wid >> 2;   // 0..1 -> 64-row half of A tile
  const int wn = wid & 3;    // 0..3 -> 64-col quarter of B tile

  f32x16 acc[2][2] = {};     // [mt][nt] -> 64 VGPRs

// one staging call: src rows R0..R0+127, LDS dest linear; wave w covers
// rows R0+16w..+16 (1 KB at region byte offset w*1024)
#define STG(LDS, SRC, TT, R0)                                                  \
  async_copy16((SRC) + (size_t)(R0) * INF + (size_t)(TT) * BK,                 \
               (const char*)(LDS) + (R0) * 64 + wid * 1024);

#define RD_ALL(S)                                                              \
  _Pragma("unroll") for (int mt = 0; mt < 2; ++mt)                             \
    _Pragma("unroll") for (int ks = 0; ks < 2; ++ks)                           \
      af[mt][ks] = *(const bf16x8*)&As[S][                                     \
          (wm * 64 + mt * 32 + rr32) * BK + (((ks * 2 + hi) ^ xr2) * 8)];      \
  _Pragma("unroll") for (int nt = 0; nt < 2; ++nt)                             \
    _Pragma("unroll") for (int ks = 0; ks < 2; ++ks)                           \
      bf[nt][ks] = *(const bf16x8*)&Bs[S][                                     \
          (wn * 64 + nt * 32 + rr32) * BK + (((ks * 2 + hi) ^ xr2) * 8)];

#define MFMA_ALL()                                                             \
  do {                                                                         \
    __builtin_amdgcn_s_setprio(1);                                             \
    _Pragma("unroll") for (int ks = 0; ks < 2; ++ks)                           \
      _Pragma("unroll") for (int mt = 0; mt < 2; ++mt)                         \
        _Pragma("unroll") for (int nt = 0; nt < 2; ++nt)                       \
          acc[mt][nt] = __builtin_amdgcn_mfma_f32_32x32x16_bf16(               \
              af[mt][ks], bf[nt][ks], acc[mt][nt], 0, 0, 0);                   \
    __builtin_amdgcn_s_setprio(0);                                             \
  } while (0)

  // prologue: tile 0 -> slot0 (3 calls), tile 1 -> slot1 (3 calls);
  // VMCNT(3) drains the oldest 3 (= all of tile 0).
  STG(&As[0][0], Asrc, 0, 0)
  STG(&Bs[0][0], Bsrc, 0, 0) STG(&Bs[0][0], Bsrc, 0, 128)
  STG(&As[1][0], Asrc, 1, 0)
  STG(&Bs[1][0], Bsrc, 1, 0) STG(&Bs[1][0], Bsrc, 1, 128)
  VMCNT(3);
  BAR();

  for (int t = 0; t < NT; ++t) {
    const int S = t & 1;
    bf16x8 af[2][2], bf[2][2];
    RD_ALL(S);
    MFMA_ALL();
    BAR();                       // all waves done reading slot S
    if (t + 2 < NT) {
      STG(&As[S][0], Asrc, t + 2, 0)
      STG(&Bs[S][0], Bsrc, t + 2, 0) STG(&Bs[S][0], Bsrc, t + 2, 128)
      VMCNT(3);                  // drains t+1's 3 calls (1 tile old)
    } else {
      VMCNT(0);
    }
    BAR();                       // t+1's staged data collectively visible
  }

  // epilogue: NT stores; 32x32 C/D layout col=lane&31,
  // row = (reg&3) + 8*(reg>>2) + 4*hi
  float bv[2];
#pragma unroll
  for (int nt = 0; nt < 2; ++nt)
    bv[nt] = bias[bn * BN + wn * 64 + nt * 32 + rr32];
#pragma unroll
  for (int mt = 0; mt < 2; ++mt)
#pragma unroll
    for (int nt = 0; nt < 2; ++nt) {
      const int gn = bn * BN + wn * 64 + nt * 32 + rr32;
#pragma unroll
      for (int reg = 0; reg < 16; ++reg) {
        const int gm = bm * BM + wm * 64 + mt * 32 +
                       (reg & 3) + 8 * (reg >> 2) + 4 * hi;
        __builtin_nontemporal_store(acc[mt][nt][reg] + bv[nt],
                                    &C[(size_t)gm * OUTF + gn]);
      }
    }
}

// ---------------- fused fallback (no workspace requirement) ----------------

#define FBM 128
#define FBN 128
#define FBK 64

#define FMFMA_COMPUTE()                                                       \
  do {                                                                        \
    const int frr = lane & 15;                                                \
    const int fq4 = lane >> 4;                                                \
    _Pragma("unroll") for (int ks = 0; ks < 2; ++ks) {                        \
      bf16x8 fa[4], fb[4];                                                    \
      const int kk = (((ks * 4 + fq4) ^ (frr & 7)) * 8);                      \
      _Pragma("unroll") for (int i = 0; i < 4; ++i) {                         \
        fa[i] = *(const bf16x8*)&Asf[(mwave + i * 16 + frr) * FBK + kk];      \
        fb[i] = *(const bf16x8*)&Bsf[(nwave + i * 16 + frr) * FBK + kk];      \
      }                                                                       \
      _Pragma("unroll") for (int mi = 0; mi < 4; ++mi)                        \
        _Pragma("unroll") for (int ni = 0; ni < 4; ++ni)                      \
          facc[mi][ni] = __builtin_amdgcn_mfma_f32_16x16x32_bf16(             \
              fa[mi], fb[ni], facc[mi][ni], 0, 0, 0);                         \
    }                                                                         \
  } while (0)

__global__ __launch_bounds__(256) void gemm_fused(const float* __restrict__ X,
                                                  const int* __restrict__ QW,
                                                  const float* __restrict__ scales,
                                                  const float* __restrict__ zeros,
                                                  const float* __restrict__ bias,
                                                  float* __restrict__ C) {
  __shared__ __align__(16) u16 Asf[FBM * FBK];
  __shared__ __align__(16) u16 Bsf[FBN * FBK];
  const int tid = threadIdx.x;
  const int lane = tid & 63;
  const int wid = tid >> 6;
  const int bm = blockIdx.y, bn = blockIdx.x;
  const int row = tid >> 1;
  const int half = tid & 1;
  const float* xr = X + (size_t)(bm * FBM + row) * INF + half * 32;
  const int* qr = QW + (size_t)(bn * FBN + row) * KB4 + half * 16;
  const float* srow = scales + (size_t)(bn * FBN + row) * NG;
  const float* zrow = zeros + (size_t)(bn * FBN + row) * NG;
  const int mwave = (wid >> 1) * 64;
  const int nwave = (wid & 1) * 64;
  f32x4 facc[4][4] = {};

  for (int kb = 0; kb < INF / FBK; ++kb) {
    const int k0 = kb * FBK;
    union { u16 t[32]; int4 v[4]; } ta, tb;
#pragma unroll
    for (int j = 0; j < 8; ++j) {
      const float4 f = *(const float4*)(xr + k0 + j * 4);
      ta.t[4 * j]     = f2bf(f.x);
      ta.t[4 * j + 1] = f2bf(f.y);
      ta.t[4 * j + 2] = f2bf(f.z);
      ta.t[4 * j + 3] = f2bf(f.w);
    }
    {
      const float s = srow[kb >> 1];
      const float zs = -zrow[kb >> 1] * s;
#pragma unroll
      for (int j = 0; j < 4; ++j) {
        const int4 q = *(const int4*)(qr + kb * 32 + j * 4);
        const int qq[4] = {q.x, q.y, q.z, q.w};
#pragma unroll
        for (int u = 0; u < 4; ++u) {
          tb.t[8 * j + 2 * u]     = f2bf(fmaf((float)(qq[u] & 15), s, zs));
          tb.t[8 * j + 2 * u + 1] = f2bf(fmaf((float)((qq[u] >> 4) & 15), s, zs));
        }
      }
    }
    __syncthreads();
#pragma unroll
    for (int j = 0; j < 4; ++j) {
      *(int4*)&Asf[row * FBK + (((half * 4 + j) ^ (row & 7)) * 8)] = ta.v[j];
      *(int4*)&Bsf[row * FBK + (((half * 4 + j) ^ (row & 7)) * 8)] = tb.v[j];
    }
    __syncthreads();
    FMFMA_COMPUTE();
  }
  {
    const int ncol = lane & 15;
    const int qrow = (lane >> 4) * 4;
#pragma unroll
    for (int mi = 0; mi < 4; ++mi)
#pragma unroll
      for (int ni = 0; ni < 4; ++ni) {
        const int gn = bn * FBN + nwave + ni * 16 + ncol;
        const float bvv = bias[gn];
#pragma unroll
        for (int r = 0; r < 4; ++r) {
          const int gm = bm * FBM + mwave + mi * 16 + qrow + r;
          C[(size_t)gm * OUTF + gn] = facc[mi][ni][r] + bvv;
        }
      }
  }
}

// ---------------- launch ----------------

extern "C" void kernel_launch(void* const* d_in, const int* in_sizes, int n_in,
                              void* d_out, int out_size, void* d_ws, size_t ws_size,
                              hipStream_t stream) {
  const float* x = (const float*)d_in[0];
  const int* qw = (const int*)d_in[1];
  const float* scales = (const float*)d_in[2];
  const float* zeros = (const float*)d_in[3];
  const float* bias = (const float*)d_in[4];
  float* out = (float*)d_out;

  const size_t needW = (size_t)OUTF * INF * sizeof(u16);  // 90,177,536 B
  const size_t needX = (size_t)TOK * INF * sizeof(u16);   // 67,108,864 B

  if (ws_size >= needW + needX) {
    u16* Wb = (u16*)d_ws;
    u16* Xb = (u16*)((char*)d_ws + needW);
    prep<<<PREPBLK, 256, 0, stream>>>(x, qw, scales, zeros, Xb, Wb);
    gemm_occ<<<dim3(NWG), 512, 0, stream>>>(Xb, Wb, bias, out);
  } else {
    gemm_fused<<<dim3(OUTF / FBN, TOK / FBM), 256, 0, stream>>>(x, qw, scales, zeros, bias, out);
  }
}

// Round 11
// 1124.508 us; speedup vs baseline: 1.1445x; 1.0812x over previous
//
#include <hip/hip_runtime.h>
#include <stdint.h>

#define OUTF 11008
#define INF  4096
#define NG   32      // groups = INF/128
#define TOK  8192
#define KB4  2048    // int32 per qweight row = INF/2

// ---- main GEMM geometry: 128x256 tile, BK=64, single-buffer A, 2 blocks/CU ----
#define BM 128
#define BN 256
#define BK 64
#define NT (INF / BK)    // 64 K-tiles
#define GX (OUTF / BN)   // 43
#define GY (TOK / BM)    // 64
#define NWG (GX * GY)    // 2752 = 8 XCD chunks x 344

typedef unsigned short u16;
typedef __attribute__((ext_vector_type(8))) short bf16x8;
typedef __attribute__((ext_vector_type(4))) float f32x4;
typedef __attribute__((ext_vector_type(16))) float f32x16;
typedef __attribute__((ext_vector_type(4))) int i32x4;

// fp32 -> bf16 round-to-nearest-even (inputs finite)
__device__ inline u16 f2bf(float f) {
  union { float f; uint32_t u; } v; v.f = f;
  return (u16)((v.u + 0x7fff + ((v.u >> 16) & 1)) >> 16);
}

// async global->LDS, 16B per lane; lds dest must be wave-uniform base (+lane*16 implicit)
__device__ inline void async_copy16(const void* g, const void* l) {
  __builtin_amdgcn_global_load_lds(
      (__attribute__((address_space(1))) void*)(g),
      (__attribute__((address_space(3))) void*)(l), 16, 0, 0);
}

#define FENCE() asm volatile("" ::: "memory")
#define BAR()   do { FENCE(); __builtin_amdgcn_s_barrier(); FENCE(); } while (0)
#define VMCNT(n) asm volatile("s_waitcnt vmcnt(" #n ")" ::: "memory")

// ---------------- fused preprocessing kernel (r8 dense version, unchanged) ----------------

#define NXU ((long long)TOK * INF / 4)    // 8,388,608
#define NWU ((long long)OUTF * KB4 / 4)   // 5,636,096
#define PREPBLK 2048

__global__ __launch_bounds__(256) void prep(const float* __restrict__ X,
                                            const int* __restrict__ QW,
                                            const float* __restrict__ scales,
                                            const float* __restrict__ zeros,
                                            u16* __restrict__ Xb,
                                            u16* __restrict__ Wb) {
  const long long stride = (long long)gridDim.x * 256;
  for (long long i = (long long)blockIdx.x * 256 + threadIdx.x; i < NXU + NWU;
       i += stride) {
    if (i < NXU) {
      const f32x4 f = __builtin_nontemporal_load((const f32x4*)X + i);
      union { u16 t[4]; uint2 v; } u;
      u.t[0] = f2bf(f[0]); u.t[1] = f2bf(f[1]);
      u.t[2] = f2bf(f[2]); u.t[3] = f2bf(f[3]);
      ((uint2*)Xb)[i] = u.v;
    } else {
      const long long j = i - NXU;          // w-unit: 4 ints of row o
      const int o = (int)(j >> 9);          // 512 units per row (2048/4)
      const int c0 = ((int)j & 511) * 4;    // int column; group = c0/64 (4 | 64)
      const int g = c0 >> 6;
      const float s = scales[o * NG + g];
      const float zs = -zeros[o * NG + g] * s;
      const i32x4 q = __builtin_nontemporal_load((const i32x4*)QW + j);
      union { u16 t[8]; int4 v; } u;
#pragma unroll
      for (int k = 0; k < 4; ++k) {
        u.t[2 * k]     = f2bf(fmaf((float)(q[k] & 15), s, zs));
        u.t[2 * k + 1] = f2bf(fmaf((float)((q[k] >> 4) & 15), s, zs));
      }
      ((int4*)Wb)[j] = u.v;                 // bf16 cols [2*c0, 2*c0+8)
    }
  }
}

// ---------------- main GEMM: 2 blocks/CU with the PROVEN r8 LDS layout ----------------
// r10's occupancy worked (21->43%) but its BK=32 64-B-row layout conflicted
// (4 cyc/read). This kernel keeps 2 blocks/CU while restoring the ONLY
// measured-zero-conflict layout (r8): 128-B rows (bank offset 0 for every
// row), 8-granule space, xr = (r&7)^((r>>3)&3), pre-swizzled global source +
// linear LDS dest. Fit in 80 KB/block via SINGLE-buffered A:
//   LDS = A[128x64] 16 KB + B[2][256x64] 64 KB = 80 KB -> 2 blocks/CU.
// A(t+1)'s staging latency is exposed at this block's end-of-tile wait; the
// partner block's MFMAs cover it (m114 wave-level overlap) -- that is the
// occupancy bet this kernel tests cleanly (conflicts removed as a confound).
//
// Wave tile 64x64 (8 waves on 128x256): wm=wid>>2 (2 m-halves), wn=wid&3
// (4 n-quarters). acc[2][2] f32x16 = 64 VGPR; JIT per-kg frag reads keep
// total ~100 VGPR (<=128 required for 4 waves/SIMD).
//
// Per tile t (B slot S=t&1), 2 barriers:
//   for kg=0..3: { A frags (2 b128) + B frags (2 b128), 4 x mfma_32x32x16 }
//   BAR   -- all waves' reads of A-buf and B slot S certified
//   stage A(t+1) (2 calls) ; stage B(t+2) -> slot S (4 calls)
//   VMCNT(4): queue (FIFO) = [B(t+1)x4 (issued t-1), A(t+1)x2, B(t+2)x4] = 10
//     -> drains B(t+1)+A(t+1) (everything tile t+1 reads), keeps B(t+2) in
//     flight (never 0 mid-loop)
//   BAR   -- drained data collectively visible
// Tail: t+2>=NT skips B stage and VMCNT(0); t+1>=NT skips A stage.
// WAR: A-buf / slot-S staging sits after the barrier certifying their reads.
// RAW: every region is read only after a VMCNT+BAR pair covering its staging.

__global__ __launch_bounds__(512, 4) void gemm_occ2(const u16* __restrict__ A,
                                                    const u16* __restrict__ B,
                                                    const float* __restrict__ bias,
                                                    float* __restrict__ C) {
  __shared__ __align__(16) u16 As[BM * BK];      // 16 KB, single-buffered
  __shared__ __align__(16) u16 Bs[2][BN * BK];   // 2 x 32 KB  (total 80 KB)
  const int tid = threadIdx.x;
  const int lane = tid & 63;
  const int wid = __builtin_amdgcn_readfirstlane(tid >> 6);

  // XCD-local 2D grouping: XCD k owns bm in [8k,8k+8); 8bm x 8bn rectangles.
  const int lin = blockIdx.x;
  const int xcd = lin & 7;
  const int wgc = lin >> 3;                 // 0..343
  int bmr, bn;
  if (wgc < 320) {
    const int g = wgc >> 6, r = wgc & 63;
    bn = g * 8 + (r & 7);
    bmr = r >> 3;
  } else {
    const int r = wgc - 320;
    bn = 40 + r % 3;
    bmr = r / 3;
  }
  const int bm = xcd * 8 + bmr;

  const u16* Ab = A + (size_t)bm * BM * INF;
  const u16* Bb = B + (size_t)bn * BN * INF;

  // staging (r8 verbatim): one global_load_lds covers 64 rows x 128 B;
  // pre-swizzled source granule, linear LDS dest
  const int rowoff = tid >> 3;                    // 0..63
  const int gran = (tid & 7) ^ (rowoff & 7) ^ ((rowoff >> 3) & 3);
  const u16* Asrc = Ab + (size_t)rowoff * INF + gran * 8;
  const u16* Bsrc = Bb + (size_t)rowoff * INF + gran * 8;
  const int wid8 = wid * 8;

  // frag addressing (32x32 MFMA, r8 layout)
  const int rr32 = lane & 31;
  const int hi = lane >> 5;
  const int xr = (rr32 & 7) ^ ((rr32 >> 3) & 3);
  const int wm = wid >> 2;   // 0..1 -> 64-row half of A tile
  const int wn = wid & 3;    // 0..3 -> 64-col quarter of B tile

  f32x16 acc[2][2] = {};     // [mt][nt] -> 64 VGPRs

#define STAGE1(LDS, SRC, TT, R0)                                               \
  async_copy16((SRC) + (size_t)(R0) * INF + (size_t)(TT) * BK,                 \
               (const char*)(LDS) + ((R0) + wid8) * 128);

// logical granule for k-slice kg (k base = kg*16 + hi*8) = kg*2 + hi
#define RD_A2(DST, KG)                                                         \
  _Pragma("unroll") for (int mt = 0; mt < 2; ++mt)                             \
    DST[mt] = *(const bf16x8*)&As[(wm * 64 + mt * 32 + rr32) * BK +            \
                                  ((((KG) * 2 + hi) ^ xr) * 8)];
#define RD_B2(DST, S, KG)                                                      \
  _Pragma("unroll") for (int nt = 0; nt < 2; ++nt)                             \
    DST[nt] = *(const bf16x8*)&Bs[S][(wn * 64 + nt * 32 + rr32) * BK +         \
                                     ((((KG) * 2 + hi) ^ xr) * 8)];

#define KGPHASE(S, KG)                                                         \
  do {                                                                         \
    bf16x8 af[2], bf[2];                                                       \
    RD_A2(af, KG) RD_B2(bf, S, KG)                                             \
    __builtin_amdgcn_s_setprio(1);                                             \
    _Pragma("unroll") for (int mt = 0; mt < 2; ++mt)                           \
      _Pragma("unroll") for (int nt = 0; nt < 2; ++nt)                         \
        acc[mt][nt] = __builtin_amdgcn_mfma_f32_32x32x16_bf16(                 \
            af[mt], bf[nt], acc[mt][nt], 0, 0, 0);                             \
    __builtin_amdgcn_s_setprio(0);                                             \
  } while (0)

  // prologue: A(0) 2 calls + B(0) 4 calls + B(1) 4 calls.
  // VMCNT(4) drains the oldest 6 (= A(0)+B(0)), keeps B(1) in flight.
  STAGE1(&As[0], Asrc, 0, 0)      STAGE1(&As[0], Asrc, 0, 64)
  STAGE1(&Bs[0][0], Bsrc, 0, 0)   STAGE1(&Bs[0][0], Bsrc, 0, 64)
  STAGE1(&Bs[0][0], Bsrc, 0, 128) STAGE1(&Bs[0][0], Bsrc, 0, 192)
  STAGE1(&Bs[1][0], Bsrc, 1, 0)   STAGE1(&Bs[1][0], Bsrc, 1, 64)
  STAGE1(&Bs[1][0], Bsrc, 1, 128) STAGE1(&Bs[1][0], Bsrc, 1, 192)
  VMCNT(4);
  BAR();

  for (int t = 0; t < NT; ++t) {
    const int S = t & 1;
    KGPHASE(S, 0); KGPHASE(S, 1); KGPHASE(S, 2); KGPHASE(S, 3);
    BAR();                       // A-buf + B slot S reads certified
    if (t + 1 < NT) { STAGE1(&As[0], Asrc, t + 1, 0) STAGE1(&As[0], Asrc, t + 1, 64) }
    if (t + 2 < NT) {
      STAGE1(&Bs[S][0], Bsrc, t + 2, 0)   STAGE1(&Bs[S][0], Bsrc, t + 2, 64)
      STAGE1(&Bs[S][0], Bsrc, t + 2, 128) STAGE1(&Bs[S][0], Bsrc, t + 2, 192)
      VMCNT(4);                  // drains B(t+1)+A(t+1); keeps B(t+2)
    } else {
      VMCNT(0);
    }
    BAR();                       // next tile's data collectively visible
  }

  // epilogue: NT stores; 32x32 C/D layout col=lane&31,
  // row = (reg&3) + 8*(reg>>2) + 4*hi
  float bv[2];
#pragma unroll
  for (int nt = 0; nt < 2; ++nt)
    bv[nt] = bias[bn * BN + wn * 64 + nt * 32 + rr32];
#pragma unroll
  for (int mt = 0; mt < 2; ++mt)
#pragma unroll
    for (int nt = 0; nt < 2; ++nt) {
      const int gn = bn * BN + wn * 64 + nt * 32 + rr32;
#pragma unroll
      for (int reg = 0; reg < 16; ++reg) {
        const int gm = bm * BM + wm * 64 + mt * 32 +
                       (reg & 3) + 8 * (reg >> 2) + 4 * hi;
        __builtin_nontemporal_store(acc[mt][nt][reg] + bv[nt],
                                    &C[(size_t)gm * OUTF + gn]);
      }
    }
}

// ---------------- fused fallback (no workspace requirement) ----------------

#define FBM 128
#define FBN 128
#define FBK 64

#define FMFMA_COMPUTE()                                                       \
  do {                                                                        \
    const int frr = lane & 15;                                                \
    const int fq4 = lane >> 4;                                                \
    _Pragma("unroll") for (int ks = 0; ks < 2; ++ks) {                        \
      bf16x8 fa[4], fb[4];                                                    \
      const int kk = (((ks * 4 + fq4) ^ (frr & 7)) * 8);                      \
      _Pragma("unroll") for (int i = 0; i < 4; ++i) {                         \
        fa[i] = *(const bf16x8*)&Asf[(mwave + i * 16 + frr) * FBK + kk];      \
        fb[i] = *(const bf16x8*)&Bsf[(nwave + i * 16 + frr) * FBK + kk];      \
      }                                                                       \
      _Pragma("unroll") for (int mi = 0; mi < 4; ++mi)                        \
        _Pragma("unroll") for (int ni = 0; ni < 4; ++ni)                      \
          facc[mi][ni] = __builtin_amdgcn_mfma_f32_16x16x32_bf16(             \
              fa[mi], fb[ni], facc[mi][ni], 0, 0, 0);                         \
    }                                                                         \
  } while (0)

__global__ __launch_bounds__(256) void gemm_fused(const float* __restrict__ X,
                                                  const int* __restrict__ QW,
                                                  const float* __restrict__ scales,
                                                  const float* __restrict__ zeros,
                                                  const float* __restrict__ bias,
                                                  float* __restrict__ C) {
  __shared__ __align__(16) u16 Asf[FBM * FBK];
  __shared__ __align__(16) u16 Bsf[FBN * FBK];
  const int tid = threadIdx.x;
  const int lane = tid & 63;
  const int wid = tid >> 6;
  const int bm = blockIdx.y, bn = blockIdx.x;
  const int row = tid >> 1;
  const int half = tid & 1;
  const float* xr = X + (size_t)(bm * FBM + row) * INF + half * 32;
  const int* qr = QW + (size_t)(bn * FBN + row) * KB4 + half * 16;
  const float* srow = scales + (size_t)(bn * FBN + row) * NG;
  const float* zrow = zeros + (size_t)(bn * FBN + row) * NG;
  const int mwave = (wid >> 1) * 64;
  const int nwave = (wid & 1) * 64;
  f32x4 facc[4][4] = {};

  for (int kb = 0; kb < INF / FBK; ++kb) {
    const int k0 = kb * FBK;
    union { u16 t[32]; int4 v[4]; } ta, tb;
#pragma unroll
    for (int j = 0; j < 8; ++j) {
      const float4 f = *(const float4*)(xr + k0 + j * 4);
      ta.t[4 * j]     = f2bf(f.x);
      ta.t[4 * j + 1] = f2bf(f.y);
      ta.t[4 * j + 2] = f2bf(f.z);
      ta.t[4 * j + 3] = f2bf(f.w);
    }
    {
      const float s = srow[kb >> 1];
      const float zs = -zrow[kb >> 1] * s;
#pragma unroll
      for (int j = 0; j < 4; ++j) {
        const int4 q = *(const int4*)(qr + kb * 32 + j * 4);
        const int qq[4] = {q.x, q.y, q.z, q.w};
#pragma unroll
        for (int u = 0; u < 4; ++u) {
          tb.t[8 * j + 2 * u]     = f2bf(fmaf((float)(qq[u] & 15), s, zs));
          tb.t[8 * j + 2 * u + 1] = f2bf(fmaf((float)((qq[u] >> 4) & 15), s, zs));
        }
      }
    }
    __syncthreads();
#pragma unroll
    for (int j = 0; j < 4; ++j) {
      *(int4*)&Asf[row * FBK + (((half * 4 + j) ^ (row & 7)) * 8)] = ta.v[j];
      *(int4*)&Bsf[row * FBK + (((half * 4 + j) ^ (row & 7)) * 8)] = tb.v[j];
    }
    __syncthreads();
    FMFMA_COMPUTE();
  }
  {
    const int ncol = lane & 15;
    const int qrow = (lane >> 4) * 4;
#pragma unroll
    for (int mi = 0; mi < 4; ++mi)
#pragma unroll
      for (int ni = 0; ni < 4; ++ni) {
        const int gn = bn * FBN + nwave + ni * 16 + ncol;
        const float bvv = bias[gn];
#pragma unroll
        for (int r = 0; r < 4; ++r) {
          const int gm = bm * FBM + mwave + mi * 16 + qrow + r;
          C[(size_t)gm * OUTF + gn] = facc[mi][ni][r] + bvv;
        }
      }
  }
}

// ---------------- launch ----------------

extern "C" void kernel_launch(void* const* d_in, const int* in_sizes, int n_in,
                              void* d_out, int out_size, void* d_ws, size_t ws_size,
                              hipStream_t stream) {
  const float* x = (const float*)d_in[0];
  const int* qw = (const int*)d_in[1];
  const float* scales = (const float*)d_in[2];
  const float* zeros = (const float*)d_in[3];
  const float* bias = (const float*)d_in[4];
  float* out = (float*)d_out;

  const size_t needW = (size_t)OUTF * INF * sizeof(u16);  // 90,177,536 B
  const size_t needX = (size_t)TOK * INF * sizeof(u16);   // 67,108,864 B

  if (ws_size >= needW + needX) {
    u16* Wb = (u16*)d_ws;
    u16* Xb = (u16*)((char*)d_ws + needW);
    prep<<<PREPBLK, 256, 0, stream>>>(x, qw, scales, zeros, Xb, Wb);
    gemm_occ2<<<dim3(NWG), 512, 0, stream>>>(Xb, Wb, bias, out);
  } else {
    gemm_fused<<<dim3(OUTF / FBN, TOK / FBM), 256, 0, stream>>>(x, qw, scales, zeros, bias, out);
  }
}